// Round 11
// baseline (98.638 us; speedup 1.0000x reference)
//
#include <hip/hip_runtime.h>
#include <math.h>

#define W 128
#define LROWS 38                   // 32 rows + 6 halo
#define TILE_IN 32
#define TILE_OUT 16
#define NTILES 4

typedef float f4 __attribute__((ext_vector_type(4)));
typedef float f2 __attribute__((ext_vector_type(2)));

__device__ __forceinline__ int refl128(int i) {
    i = (i < 0) ? (-1 - i) : i;    // symmetric (half-sample) reflect
    return (i > 127) ? (255 - i) : i;
}

// packed magnitude for two output columns at once
__device__ __forceinline__ f2 mag2(f2 re, f2 im) {
    f2 t = re * re + im * im + 1.0e-4f;
    f2 s = __builtin_elementwise_sqrt(t);
    return s - 0.01f;
}

__device__ __forceinline__ void st2v(float* p, f2 v) {
    *(f2*)p = v;                   // plain cached store (A/B vs NT)
}

// q2c + magnitudes: t = top full-res row (4 cols), b = bottom row
__device__ __forceinline__ void q2c(f4 t, f4 b, f2& mneg, f2& mpos) {
    const f2 e  = __builtin_shufflevector(t, t, 0, 2);
    const f2 eo = __builtin_shufflevector(t, t, 1, 3);
    const f2 o  = __builtin_shufflevector(b, b, 1, 3);
    const f2 oo = __builtin_shufflevector(b, b, 0, 2);
    mneg = mag2(e - o, eo + oo);
    mpos = mag2(e + o, eo - oo);
}

__global__ __launch_bounds__(256) void scat_j1_kernel(
    const float* __restrict__ x,
    float* __restrict__ out_ll,
    float* __restrict__ out_r)
{
    __shared__ float slo[LROWS][W];
    __shared__ float shi[LROWS][W];

    // XCD-chunked swizzle: grid 8192 = 8 * 1024, bijective.
    const int raw   = blockIdx.x;
    const int L_id  = (raw & 7) * 1024 + (raw >> 3);
    const int plane = L_id >> 2;       // n*64 + c   (0..2047)
    const int tile  = L_id & 3;        // 0..3
    const int r0    = tile * TILE_IN;
    const int tid   = threadIdx.x;

    const float* __restrict__ xp = x + (size_t)plane * (W * W);

    // ---- Phase 1: horizontal 5/7-tap filters (packed), write lo/hi to LDS ----
    {
        const int g  = tid & 31;       // 4-col group 0..31
        const int rb = tid >> 5;       // 0..7 row within pass
        #pragma unroll
        for (int it = 0; it < 5; ++it) {
            const int lr = it * 8 + rb;           // 0..39
            if (lr < LROWS) {                     // wave-uniform guard
                const int q = refl128(r0 - 3 + lr);
                const f4* __restrict__ rv = (const f4*)(xp + (size_t)q * W);
                const f4 B = rv[g];
                f4 A = rv[g > 0 ? g - 1 : 0];
                f4 C = rv[g < 31 ? g + 1 : 31];
                const f4 revB = __builtin_shufflevector(B, B, 3, 2, 1, 0);
                if (g == 0)  A = revB;            // cols -4..-1 reflected
                if (g == 31) C = revB;            // cols 128..131 reflected
                const f4 m0 = __builtin_shufflevector(A, B, 1, 2, 3, 4);
                const f4 m1 = __builtin_shufflevector(A, B, 2, 3, 4, 5);
                const f4 m2 = __builtin_shufflevector(A, B, 3, 4, 5, 6);
                const f4 m3 = B;
                const f4 m4 = __builtin_shufflevector(B, C, 1, 2, 3, 4);
                const f4 m5 = __builtin_shufflevector(B, C, 2, 3, 4, 5);
                const f4 m6 = __builtin_shufflevector(B, C, 3, 4, 5, 6);
                const f4 s06 = m0 + m6;
                const f4 s15 = m1 + m5;
                const f4 s24 = m2 + m4;
                const f4 lo4 = -0.05f * s15 + 0.25f * s24 + 0.5f * m3;
                const f4 hi4 = -0.0107143f * s06 + 0.0535714f * s15
                             +  0.2607143f * s24 + -0.6071429f * m3;
                ((f4*)&slo[lr][0])[g] = lo4;
                ((f4*)&shi[lr][0])[g] = hi4;
            }
        }
    }
    __syncthreads();

    // ---- Phase 2: 2 half-rows/thread from a 10-row register window ----
    // thread = (col-pair cp 0..31 -> output cols 2cp,2cp+1; Ib 0..7 -> half-rows 2Ib,2Ib+1)
    const int cp = tid & 31;
    const int Ib = tid >> 5;
    const int R0 = 4 * Ib;             // LDS window start
    const int n  = plane >> 6;
    const int ch = plane & 63;

    // band taps folded with 1/sqrt(2); ll taps folded with 0.25
    const float S   = 0.70710678118654752f;
    const float a7  = -0.0107143f * S, b7 = 0.0535714f * S,
                c7  =  0.2607143f * S, d7 = -0.6071429f * S;
    const float a5s = -0.05f * S, b5s = 0.25f * S, c5s = 0.5f * S;
    const float p5a = -0.0125f, p5b = 0.0625f, p5c = 0.125f;

    const int I0 = tile * TILE_OUT + 2 * Ib;
    float* llp = out_ll + (size_t)plane * 4096 + (size_t)I0 * 64 + 2 * cp;
    float* rp  = out_r + ((size_t)(n * 384 + ch)) * 4096 + (size_t)I0 * 64 + 2 * cp;

    {   // L band: lh (15/165) + ll
        f4 v[10];
        #pragma unroll
        for (int t = 0; t < 10; ++t) v[t] = ((const f4*)&slo[R0 + t][0])[cp];
        #pragma unroll
        for (int k = 0; k < 2; ++k) {
            const f4* w = v + 2 * k;   // window rows for half-row 2Ib+k
            const f4 s15 = w[1] + w[5], s24 = w[2] + w[4];
            const f4 s26 = w[2] + w[6], s35 = w[3] + w[5];
            const f4 t7 = a7 * (w[0] + w[6]) + b7 * s15 + c7 * s24 + d7 * w[3];
            const f4 bo = a7 * (w[1] + w[7]) + b7 * s26 + c7 * s35 + d7 * w[4];
            f2 m15, m165;
            q2c(t7, bo, m15, m165);
            const f4 lt = p5a * s15 + p5b * s24 + p5c * w[3];
            const f4 lb = p5a * s26 + p5b * s35 + p5c * w[4];
            const f4 sl = lt + lb;
            f2 llv;
            llv.x = sl.x + sl.y;
            llv.y = sl.z + sl.w;
            st2v(llp + k * 64, llv);
            st2v(rp + k * 64 + 0u * 262144u, m15);
            st2v(rp + k * 64 + 5u * 262144u, m165);
        }
    }
    {   // H band: hh (45/135) + hl (75/105)
        f4 v[10];
        #pragma unroll
        for (int t = 0; t < 10; ++t) v[t] = ((const f4*)&shi[R0 + t][0])[cp];
        #pragma unroll
        for (int k = 0; k < 2; ++k) {
            const f4* w = v + 2 * k;
            const f4 s15 = w[1] + w[5], s24 = w[2] + w[4];
            const f4 s26 = w[2] + w[6], s35 = w[3] + w[5];
            const f4 t7 = a7 * (w[0] + w[6]) + b7 * s15 + c7 * s24 + d7 * w[3];
            const f4 bo = a7 * (w[1] + w[7]) + b7 * s26 + c7 * s35 + d7 * w[4];
            f2 m45, m135;
            q2c(t7, bo, m45, m135);
            const f4 ht = a5s * s15 + b5s * s24 + c5s * w[3];
            const f4 hb = a5s * s26 + b5s * s35 + c5s * w[4];
            f2 m75, m105;
            q2c(ht, hb, m75, m105);
            st2v(rp + k * 64 + 1u * 262144u, m45);
            st2v(rp + k * 64 + 2u * 262144u, m75);
            st2v(rp + k * 64 + 3u * 262144u, m105);
            st2v(rp + k * 64 + 4u * 262144u, m135);
        }
    }
}

extern "C" void kernel_launch(void* const* d_in, const int* in_sizes, int n_in,
                              void* d_out, int out_size, void* d_ws, size_t ws_size,
                              hipStream_t stream) {
    const float* x = (const float*)d_in[0];
    float* out = (float*)d_out;
    float* out_ll = out;                 // 32*64*64*64 = 8388608 floats
    float* out_r  = out + 8388608;       // 32*384*64*64 = 50331648 floats

    dim3 grid(2048 * NTILES);            // (n*c) planes * 4 row-tiles
    dim3 block(256);
    hipLaunchKernelGGL(scat_j1_kernel, grid, block, 0, stream, x, out_ll, out_r);
}

// Round 12
// 77.966 us; speedup vs baseline: 1.2651x; 1.2651x over previous
//
#include <hip/hip_runtime.h>
#include <math.h>

#define W 128
#define LROWS 38                   // 32 rows + 6 halo
#define TILE_IN 32
#define TILE_OUT 16
#define NTILES 4

typedef float f4 __attribute__((ext_vector_type(4)));
typedef float f2 __attribute__((ext_vector_type(2)));

__device__ __forceinline__ int refl128(int i) {
    i = (i < 0) ? (-1 - i) : i;    // symmetric (half-sample) reflect
    return (i > 127) ? (255 - i) : i;
}

// packed magnitude for two output columns at once
__device__ __forceinline__ f2 mag2(f2 re, f2 im) {
    f2 t = re * re + im * im + 1.0e-4f;
    f2 s = __builtin_elementwise_sqrt(t);
    return s - 0.01f;
}

__device__ __forceinline__ void st4v(float* p, f4 v) {
    __builtin_nontemporal_store(v, (f4*)p);    // 16 B/lane NT store
}

// q2c + magnitudes: t = top full-res row (4 cols), b = bottom row
__device__ __forceinline__ void q2c(f4 t, f4 b, f2& mneg, f2& mpos) {
    const f2 e  = __builtin_shufflevector(t, t, 0, 2);
    const f2 eo = __builtin_shufflevector(t, t, 1, 3);
    const f2 o  = __builtin_shufflevector(b, b, 1, 3);
    const f2 oo = __builtin_shufflevector(b, b, 0, 2);
    mneg = mag2(e - o, eo + oo);
    mpos = mag2(e + o, eo - oo);
}

__global__ __launch_bounds__(256) void scat_j1_kernel(
    const float* __restrict__ x,
    float* __restrict__ out_ll,
    float* __restrict__ out_r)
{
    __shared__ float slo[LROWS][W];
    __shared__ float shi[LROWS][W];

    // XCD-chunked swizzle: grid 8192 = 8 * 1024, bijective.
    const int raw   = blockIdx.x;
    const int L_id  = (raw & 7) * 1024 + (raw >> 3);
    const int plane = L_id >> 2;       // n*64 + c   (0..2047)
    const int tile  = L_id & 3;        // 0..3
    const int r0    = tile * TILE_IN;
    const int tid   = threadIdx.x;

    const float* __restrict__ xp = x + (size_t)plane * (W * W);

    // ---- Phase 1: horizontal 5/7-tap filters (packed), write lo/hi to LDS ----
    {
        const int g  = tid & 31;       // 4-col group 0..31
        const int rb = tid >> 5;       // 0..7 row within pass
        #pragma unroll
        for (int it = 0; it < 5; ++it) {
            const int lr = it * 8 + rb;           // 0..39
            if (lr < LROWS) {                     // wave-uniform guard
                const int q = refl128(r0 - 3 + lr);
                const f4* __restrict__ rv = (const f4*)(xp + (size_t)q * W);
                const f4 B = rv[g];
                f4 A = rv[g > 0 ? g - 1 : 0];
                f4 C = rv[g < 31 ? g + 1 : 31];
                const f4 revB = __builtin_shufflevector(B, B, 3, 2, 1, 0);
                if (g == 0)  A = revB;            // cols -4..-1 reflected
                if (g == 31) C = revB;            // cols 128..131 reflected
                const f4 m0 = __builtin_shufflevector(A, B, 1, 2, 3, 4);
                const f4 m1 = __builtin_shufflevector(A, B, 2, 3, 4, 5);
                const f4 m2 = __builtin_shufflevector(A, B, 3, 4, 5, 6);
                const f4 m3 = B;
                const f4 m4 = __builtin_shufflevector(B, C, 1, 2, 3, 4);
                const f4 m5 = __builtin_shufflevector(B, C, 2, 3, 4, 5);
                const f4 m6 = __builtin_shufflevector(B, C, 3, 4, 5, 6);
                const f4 s06 = m0 + m6;
                const f4 s15 = m1 + m5;
                const f4 s24 = m2 + m4;
                const f4 lo4 = -0.05f * s15 + 0.25f * s24 + 0.5f * m3;
                const f4 hi4 = -0.0107143f * s06 + 0.0535714f * s15
                             +  0.2607143f * s24 + -0.6071429f * m3;
                ((f4*)&slo[lr][0])[g] = lo4;
                ((f4*)&shi[lr][0])[g] = hi4;
            }
        }
    }
    __syncthreads();

    // ---- Phase 2: one half-row x 4 output cols per thread; b128 NT stores ----
    // thread = (col-quad cq 0..15 -> output cols 4cq..4cq+3; Ib 0..15 -> half-row)
    // A wave's 64 lanes cover 4 adjacent rows x 64 cols = 1024 B contiguous/store.
    const int cq = tid & 15;
    const int Ib = tid >> 4;
    const int R0 = 2 * Ib;             // LDS window start
    const int n  = plane >> 6;
    const int ch = plane & 63;

    // band taps folded with 1/sqrt(2); ll taps folded with 0.25
    const float S   = 0.70710678118654752f;
    const float a7  = -0.0107143f * S, b7 = 0.0535714f * S,
                c7  =  0.2607143f * S, d7 = -0.6071429f * S;
    const float a5s = -0.05f * S, b5s = 0.25f * S, c5s = 0.5f * S;
    const float p5a = -0.0125f, p5b = 0.0625f, p5c = 0.125f;

    const int I = tile * TILE_OUT + Ib;
    float* llp = out_ll + (size_t)plane * 4096 + (size_t)I * 64 + 4 * cq;
    float* rp  = out_r + ((size_t)(n * 384 + ch)) * 4096 + (size_t)I * 64 + 4 * cq;

    {   // L band: lh (15/165) + ll
        f4 m15, m165, llv;
        #pragma unroll
        for (int cg = 0; cg < 2; ++cg) {
            f4 v[8];
            #pragma unroll
            for (int t = 0; t < 8; ++t)
                v[t] = ((const f4*)&slo[R0 + t][0])[2 * cq + cg];
            const f4 s15 = v[1] + v[5], s24 = v[2] + v[4];
            const f4 s26 = v[2] + v[6], s35 = v[3] + v[5];
            const f4 t7 = a7 * (v[0] + v[6]) + b7 * s15 + c7 * s24 + d7 * v[3];
            const f4 bo = a7 * (v[1] + v[7]) + b7 * s26 + c7 * s35 + d7 * v[4];
            f2 mn, mp;
            q2c(t7, bo, mn, mp);
            const f4 lt = p5a * s15 + p5b * s24 + p5c * v[3];
            const f4 lb = p5a * s26 + p5b * s35 + p5c * v[4];
            const f4 sl = lt + lb;
            if (cg == 0) {
                m15.x = mn.x;  m15.y = mn.y;
                m165.x = mp.x; m165.y = mp.y;
                llv.x = sl.x + sl.y; llv.y = sl.z + sl.w;
            } else {
                m15.z = mn.x;  m15.w = mn.y;
                m165.z = mp.x; m165.w = mp.y;
                llv.z = sl.x + sl.y; llv.w = sl.z + sl.w;
            }
        }
        st4v(llp, llv);
        st4v(rp + 0u * 262144u, m15);
        st4v(rp + 5u * 262144u, m165);
    }
    {   // H band: hh (45/135) + hl (75/105)
        f4 m45, m135, m75, m105;
        #pragma unroll
        for (int cg = 0; cg < 2; ++cg) {
            f4 v[8];
            #pragma unroll
            for (int t = 0; t < 8; ++t)
                v[t] = ((const f4*)&shi[R0 + t][0])[2 * cq + cg];
            const f4 s15 = v[1] + v[5], s24 = v[2] + v[4];
            const f4 s26 = v[2] + v[6], s35 = v[3] + v[5];
            const f4 t7 = a7 * (v[0] + v[6]) + b7 * s15 + c7 * s24 + d7 * v[3];
            const f4 bo = a7 * (v[1] + v[7]) + b7 * s26 + c7 * s35 + d7 * v[4];
            f2 mn, mp;
            q2c(t7, bo, mn, mp);
            const f4 ht = a5s * s15 + b5s * s24 + c5s * v[3];
            const f4 hb = a5s * s26 + b5s * s35 + c5s * v[4];
            f2 hn, hp;
            q2c(ht, hb, hn, hp);
            if (cg == 0) {
                m45.x = mn.x;  m45.y = mn.y;
                m135.x = mp.x; m135.y = mp.y;
                m75.x = hn.x;  m75.y = hn.y;
                m105.x = hp.x; m105.y = hp.y;
            } else {
                m45.z = mn.x;  m45.w = mn.y;
                m135.z = mp.x; m135.w = mp.y;
                m75.z = hn.x;  m75.w = hn.y;
                m105.z = hp.x; m105.w = hp.y;
            }
        }
        st4v(rp + 1u * 262144u, m45);
        st4v(rp + 2u * 262144u, m75);
        st4v(rp + 3u * 262144u, m105);
        st4v(rp + 4u * 262144u, m135);
    }
}

extern "C" void kernel_launch(void* const* d_in, const int* in_sizes, int n_in,
                              void* d_out, int out_size, void* d_ws, size_t ws_size,
                              hipStream_t stream) {
    const float* x = (const float*)d_in[0];
    float* out = (float*)d_out;
    float* out_ll = out;                 // 32*64*64*64 = 8388608 floats
    float* out_r  = out + 8388608;       // 32*384*64*64 = 50331648 floats

    dim3 grid(2048 * NTILES);            // (n*c) planes * 4 row-tiles
    dim3 block(256);
    hipLaunchKernelGGL(scat_j1_kernel, grid, block, 0, stream, x, out_ll, out_r);
}